// Round 4
// baseline (527.623 us; speedup 1.0000x reference)
//
#include <hip/hip_runtime.h>
#include <hip/hip_bf16.h>

#define N 8192
#define HID 64
#define JC 16   // J-chunks per I-tile for sums_kernel: grid = 128*JC blocks

typedef __attribute__((ext_vector_type(4))) float f32x4;
typedef __attribute__((ext_vector_type(8))) __bf16 bf16x8;

// ---------------- Kernel A: projection + L2 normalize -> bf16 ----------------
// h = elu(x @ W1^T + b1); z = h @ W2^T + b2; zhat = z / max(||z||, 1e-12)
// One wave per row-iteration; lane j = output feature j. W1/W2 in LDS with
// stride-68 padding (conflict-free f32x4 reads). 1024 blocks -> 4 rows/wave.
__global__ __launch_bounds__(256) void proj_kernel(
    const float* __restrict__ x1, const float* __restrict__ x2,
    const float* __restrict__ W1, const float* __restrict__ b1,
    const float* __restrict__ W2, const float* __restrict__ b2,
    __bf16* __restrict__ Z1h, __bf16* __restrict__ Z2h)
{
  __shared__ __align__(16) float w1s[64*68];
  __shared__ __align__(16) float w2s[64*68];
  __shared__ __align__(16) float xs[4][64];
  __shared__ __align__(16) float hs[4][64];

  const int tid  = threadIdx.x;
  const int lane = tid & 63;
  const int w    = tid >> 6;

  for (int idx = tid; idx < 64*64; idx += 256) {
    int j = idx >> 6, k = idx & 63;
    w1s[j*68+k] = W1[idx];
    w2s[j*68+k] = W2[idx];
  }
  __syncthreads();

  const float bias1 = b1[lane];
  const float bias2 = b2[lane];

  const int wave_global = blockIdx.x * 4 + w;   // 0..4095 with grid=1024
  #pragma unroll 1
  for (int it = 0; it < 4; ++it) {
    int R = wave_global * 4 + it;               // 0..16383
    const float* src; __bf16* dst;
    if (R < N) { src = x1 + (size_t)R*HID;      dst = Z1h + (size_t)R*HID; }
    else       { src = x2 + (size_t)(R-N)*HID;  dst = Z2h + (size_t)(R-N)*HID; }

    float xv = src[lane];
    xs[w][lane] = xv;
    float acc = bias1;
    #pragma unroll
    for (int qq = 0; qq < 16; ++qq) {
      f32x4 xq = *(const f32x4*)&xs[w][qq*4];            // broadcast read
      f32x4 wq = *(const f32x4*)&w1s[lane*68 + qq*4];
      acc += xq.x*wq.x + xq.y*wq.y + xq.z*wq.z + xq.w*wq.w;
    }
    float h = acc > 0.f ? acc : expm1f(acc);             // ELU (alpha=1)
    hs[w][lane] = h;
    float acc2 = bias2;
    #pragma unroll
    for (int qq = 0; qq < 16; ++qq) {
      f32x4 hq = *(const f32x4*)&hs[w][qq*4];
      f32x4 wq = *(const f32x4*)&w2s[lane*68 + qq*4];
      acc2 += hq.x*wq.x + hq.y*wq.y + hq.z*wq.z + hq.w*wq.w;
    }
    float z = acc2;
    float ss = z*z;
    #pragma unroll
    for (int m = 1; m < 64; m <<= 1) ss += __shfl_xor(ss, m);
    float inv = 1.0f / fmaxf(sqrtf(ss), 1e-12f);
    dst[lane] = (__bf16)(z * inv);
  }
}

// ---------------- Kernel B1: sparse positive scan -> num1/num2 ----------------
// pos is binary with ~0.5% density. One wave per row: stream the 32KB pos row
// at HBM bandwidth (f32x4 per lane, 2-deep prefetch). For each nonzero column j
// (ballot + mask loop, wave-uniform body — ballot result is identical across
// lanes, so no divergence), all 64 lanes cooperate on the two 64-dim dots
// (HID == wavefront size: one lane per dim, Z rows L2-resident):
//   num1[i] += exp(z1_i.z2_j / tau),  num2[i] += exp(z2_i.z1_j / tau)
// Row owned by exactly one wave -> plain store, no atomics.
__global__ __launch_bounds__(256) void scan_kernel(
    const float* __restrict__ pos,
    const __bf16* __restrict__ Z1h, const __bf16* __restrict__ Z2h,
    float* __restrict__ num1, float* __restrict__ num2)
{
  const int tid  = threadIdx.x;
  const int lane = tid & 63;
  const int w    = tid >> 6;
  const int row  = blockIdx.x * 4 + w;          // grid 2048 -> rows 0..8191
  if (row >= N) return;

  const float z1i = (float)Z1h[(size_t)row*HID + lane];
  const float z2i = (float)Z2h[(size_t)row*HID + lane];
  const float Cexp = 1.8033688011112042f;       // 1/(TAU*ln2), TAU=0.8
  const float* prow = pos + (size_t)row * N;

  float n1 = 0.f, n2 = 0.f;

  f32x4 v = *(const f32x4*)(prow + lane*4);
  #pragma unroll 1
  for (int it = 0; it < N/256; ++it) {          // 32 iterations x 1KB/wave
    // prefetch next chunk; clamp addr on last iter (data unused, stays in-bounds)
    int itn = (it < N/256 - 1) ? (it + 1) : it;
    f32x4 vn = *(const f32x4*)(prow + itn*256 + lane*4);
    #pragma unroll
    for (int s = 0; s < 4; ++s) {
      unsigned long long m = __ballot(v[s] != 0.0f);
      while (m) {
        int l = __ffsll(m) - 1;
        m &= m - 1;
        int j = it*256 + l*4 + s;
        float z1j = (float)Z1h[(size_t)j*HID + lane];
        float z2j = (float)Z2h[(size_t)j*HID + lane];
        float d1 = z1i * z2j;                   // -> T1[i][j]
        float d2 = z2i * z1j;                   // -> T2[i][j] = T1[j][i]
        #pragma unroll
        for (int mm = 1; mm < 64; mm <<= 1) {
          d1 += __shfl_xor(d1, mm);
          d2 += __shfl_xor(d2, mm);
        }
        n1 += exp2f(d1 * Cexp);
        n2 += exp2f(d2 * Cexp);
      }
    }
    v = vn;
  }
  if (lane == 0) { num1[row] = n1; num2[row] = n2; }
}

// ---------------- Kernel B2: dense exp-sim row sums (no pos reads) ----------
// Per wave: 16 I-rows fixed (A-frags in registers), sweep J in 32-col steps.
// Both exp-sim matrices' row sums (rowsum1 = rows of exp(Z1 Z2^T/tau),
// rowsum2 = rows of exp(Z2 Z1^T/tau)) from the same loaded j-fragments.
// Pure L2-resident traffic (Z1h+Z2h = 2MB); MFMA layouts verified earlier
// (element (i = i0+q*4+r, j = j0+c*16+r16), absmax 0).
__global__ __launch_bounds__(256) void sums_kernel(
    const __bf16* __restrict__ Z1h, const __bf16* __restrict__ Z2h,
    float* __restrict__ rowsum1, float* __restrict__ rowsum2)
{
  const int tid  = threadIdx.x;
  const int lane = tid & 63;
  const int w    = tid >> 6;
  const int r16  = lane & 15;
  const int q    = lane >> 4;

  const int bi = blockIdx.x / JC;   // 0..127 I-tile
  const int jc = blockIdx.x % JC;
  const int i0 = bi*64 + w*16;

  const __bf16* z1r = Z1h + (size_t)(i0 + r16)*HID + q*8;
  const __bf16* z2r = Z2h + (size_t)(i0 + r16)*HID + q*8;
  const bf16x8 a1lo = *(const bf16x8*)(z1r);
  const bf16x8 a1hi = *(const bf16x8*)(z1r + 32);
  const bf16x8 a2lo = *(const bf16x8*)(z2r);
  const bf16x8 a2hi = *(const bf16x8*)(z2r + 32);

  float s1[4] = {0.f,0.f,0.f,0.f};
  float s2[4] = {0.f,0.f,0.f,0.f};

  const int jbeg = jc * (N/JC);
  const int jend = jbeg + (N/JC);
  const float Cexp = 1.8033688011112042f;  // 1/(TAU*ln2), TAU=0.8

  #pragma unroll 1
  for (int j0 = jbeg; j0 < jend; j0 += 32) {
    bf16x8 b2l[2], b2h[2], b1l[2], b1h[2];
    #pragma unroll
    for (int c = 0; c < 2; ++c) {
      const __bf16* zb2 = Z2h + (size_t)(j0 + c*16 + r16)*HID + q*8;
      const __bf16* zb1 = Z1h + (size_t)(j0 + c*16 + r16)*HID + q*8;
      b2l[c] = *(const bf16x8*)(zb2);
      b2h[c] = *(const bf16x8*)(zb2 + 32);
      b1l[c] = *(const bf16x8*)(zb1);
      b1h[c] = *(const bf16x8*)(zb1 + 32);
    }
    #pragma unroll
    for (int c = 0; c < 2; ++c) {
      f32x4 zero4 = {0.f,0.f,0.f,0.f};
      f32x4 d1 = __builtin_amdgcn_mfma_f32_16x16x32_bf16(a1lo, b2l[c], zero4, 0,0,0);
      d1       = __builtin_amdgcn_mfma_f32_16x16x32_bf16(a1hi, b2h[c], d1,    0,0,0);
      f32x4 d2 = __builtin_amdgcn_mfma_f32_16x16x32_bf16(a2lo, b1l[c], zero4, 0,0,0);
      d2       = __builtin_amdgcn_mfma_f32_16x16x32_bf16(a2hi, b1h[c], d2,    0,0,0);
      #pragma unroll
      for (int r = 0; r < 4; ++r) {
        s1[r] += exp2f(d1[r] * Cexp);
        s2[r] += exp2f(d2[r] * Cexp);
      }
    }
  }

  // reduce across the 16 lanes of each quad (cols), leaving per-row sums
  #pragma unroll
  for (int r = 0; r < 4; ++r) {
    #pragma unroll
    for (int m = 1; m < 16; m <<= 1) {
      s1[r] += __shfl_xor(s1[r], m);
      s2[r] += __shfl_xor(s2[r], m);
    }
  }
  if (r16 == 0) {
    #pragma unroll
    for (int r = 0; r < 4; ++r) {
      int rowi = i0 + q*4 + r;
      atomicAdd(&rowsum1[rowi], s1[r]);
      atomicAdd(&rowsum2[rowi], s2[r]);
    }
  }
}

// ---------------- Kernel C: final loss reduction ----------------
__global__ __launch_bounds__(1024) void loss_kernel(
    const float* __restrict__ rowsum1, const float* __restrict__ num1,
    const float* __restrict__ rowsum2, const float* __restrict__ num2,
    float* __restrict__ out)
{
  __shared__ float part[16];
  const int tid = threadIdx.x, lane = tid & 63, w = tid >> 6;
  float acc = 0.f;
  for (int i = tid; i < N; i += 1024) {
    float sc = -logf(num1[i]/(rowsum1[i]+1e-8f) + 1e-8f);
    float mp = -logf(num2[i]/(rowsum2[i]+1e-8f) + 1e-8f);
    acc += 0.5f*sc + 0.5f*mp;   // LAMBDA = 0.5
  }
  #pragma unroll
  for (int m = 1; m < 64; m <<= 1) acc += __shfl_xor(acc, m);
  if (lane == 0) part[w] = acc;
  __syncthreads();
  if (tid == 0) {
    float t = 0.f;
    #pragma unroll
    for (int k = 0; k < 16; ++k) t += part[k];
    out[0] = t * (1.0f/N);
  }
}

extern "C" void kernel_launch(void* const* d_in, const int* in_sizes, int n_in,
                              void* d_out, int out_size, void* d_ws, size_t ws_size,
                              hipStream_t stream) {
  const float* x1  = (const float*)d_in[0];
  const float* x2  = (const float*)d_in[1];
  const float* W1  = (const float*)d_in[2];
  const float* b1  = (const float*)d_in[3];
  const float* W2  = (const float*)d_in[4];
  const float* b2  = (const float*)d_in[5];
  const float* pos = (const float*)d_in[6];

  char* ws = (char*)d_ws;
  __bf16* Z1h = (__bf16*)ws;
  __bf16* Z2h = (__bf16*)(ws + (size_t)N*HID*sizeof(__bf16));
  size_t zbytes = (size_t)2*N*HID*sizeof(__bf16);   // 2 MB
  float* rowsum1 = (float*)(ws + zbytes);
  float* num1    = rowsum1 + N;
  float* rowsum2 = num1 + N;
  float* num2    = rowsum2 + N;

  hipMemsetAsync(ws + zbytes, 0, (size_t)4*N*sizeof(float), stream);
  proj_kernel<<<1024, 256, 0, stream>>>(x1, x2, W1, b1, W2, b2, Z1h, Z2h);
  scan_kernel<<<2048, 256, 0, stream>>>(pos, Z1h, Z2h, num1, num2);
  sums_kernel<<<128*JC, 256, 0, stream>>>(Z1h, Z2h, rowsum1, rowsum2);
  loss_kernel<<<1, 1024, 0, stream>>>(rowsum1, num1, rowsum2, num2, (float*)d_out);
}

// Round 5
// 462.443 us; speedup vs baseline: 1.1409x; 1.1409x over previous
//
#include <hip/hip_runtime.h>
#include <hip/hip_bf16.h>

#define N 8192
#define HID 64
#define JC 16   // J-chunks per I-tile: grid = 128*JC blocks

typedef __attribute__((ext_vector_type(4))) float f32x4;
typedef __attribute__((ext_vector_type(8))) __bf16 bf16x8;

// ---------------- Kernel A: projection + L2 normalize -> bf16 ----------------
// h = elu(x @ W1^T + b1); z = h @ W2^T + b2; zhat = z / max(||z||, 1e-12)
// One wave per row-iteration; lane j = output feature j. W1/W2 in LDS with
// stride-68 padding (conflict-free f32x4 reads). 1024 blocks -> 4 rows/wave.
// Also zero-inits the 4*N stat array (replaces a hipMemsetAsync dispatch;
// stream ordering guarantees sim_kernel sees the zeros).
__global__ __launch_bounds__(256) void proj_kernel(
    const float* __restrict__ x1, const float* __restrict__ x2,
    const float* __restrict__ W1, const float* __restrict__ b1,
    const float* __restrict__ W2, const float* __restrict__ b2,
    __bf16* __restrict__ Z1h, __bf16* __restrict__ Z2h,
    float* __restrict__ stats)
{
  __shared__ __align__(16) float w1s[64*68];
  __shared__ __align__(16) float w2s[64*68];
  __shared__ __align__(16) float xs[4][64];
  __shared__ __align__(16) float hs[4][64];

  const int tid  = threadIdx.x;
  const int lane = tid & 63;
  const int w    = tid >> 6;

  // zero rowsum1/num1/rowsum2/num2 (4*N floats, contiguous)
  int gtid = blockIdx.x * 256 + tid;
  if (gtid < 4*N) stats[gtid] = 0.f;

  for (int idx = tid; idx < 64*64; idx += 256) {
    int j = idx >> 6, k = idx & 63;
    w1s[j*68+k] = W1[idx];
    w2s[j*68+k] = W2[idx];
  }
  __syncthreads();

  const float bias1 = b1[lane];
  const float bias2 = b2[lane];

  const int wave_global = blockIdx.x * 4 + w;   // 0..4095 with grid=1024
  #pragma unroll 1
  for (int it = 0; it < 4; ++it) {
    int R = wave_global * 4 + it;               // 0..16383
    const float* src; __bf16* dst;
    if (R < N) { src = x1 + (size_t)R*HID;      dst = Z1h + (size_t)R*HID; }
    else       { src = x2 + (size_t)(R-N)*HID;  dst = Z2h + (size_t)(R-N)*HID; }

    float xv = src[lane];
    xs[w][lane] = xv;
    float acc = bias1;
    #pragma unroll
    for (int qq = 0; qq < 16; ++qq) {
      f32x4 xq = *(const f32x4*)&xs[w][qq*4];            // broadcast read
      f32x4 wq = *(const f32x4*)&w1s[lane*68 + qq*4];
      acc += xq.x*wq.x + xq.y*wq.y + xq.z*wq.z + xq.w*wq.w;
    }
    float h = acc > 0.f ? acc : expm1f(acc);             // ELU (alpha=1)
    hs[w][lane] = h;
    float acc2 = bias2;
    #pragma unroll
    for (int qq = 0; qq < 16; ++qq) {
      f32x4 hq = *(const f32x4*)&hs[w][qq*4];
      f32x4 wq = *(const f32x4*)&w2s[lane*68 + qq*4];
      acc2 += hq.x*wq.x + hq.y*wq.y + hq.z*wq.z + hq.w*wq.w;
    }
    float z = acc2;
    float ss = z*z;
    #pragma unroll
    for (int m = 1; m < 64; m <<= 1) ss += __shfl_xor(ss, m);
    float inv = 1.0f / fmaxf(sqrtf(ss), 1e-12f);
    dst[lane] = (__bf16)(z * inv);
  }
}

// ---------------- Kernel B: tiled exp-sim accumulation (swapped, no pipe) ---
// Swapped-operand MFMA: d = mfma(zj_frag, zi_frag) -> D[row=j-local][col=i-local].
// Lane (q,r16), reg r holds element (i = i0+r16, j = j0+c*16+q*4+r), so each
// lane's pos values for a c-tile are ONE aligned f32x4 (verified absmax 0 in R1).
// vs R0: 10 load insts/step instead of 16 (8 frag + 2 dwordx4 pos vs 8 frag +
// 8 strided scalar pos); accumulators are 4 scalars (sum over j is lane-local).
// vs R1: NO register double-buffer -> VGPR back to ~R0 level, occupancy ~50%.
__global__ __launch_bounds__(256) void sim_kernel(
    const __bf16* __restrict__ Z1h, const __bf16* __restrict__ Z2h,
    const float* __restrict__ pos,
    float* __restrict__ rowsum1, float* __restrict__ num1,
    float* __restrict__ rowsum2, float* __restrict__ num2)
{
  const int tid  = threadIdx.x;
  const int lane = tid & 63;
  const int w    = tid >> 6;
  const int r16  = lane & 15;
  const int q    = lane >> 4;

  const int bi = blockIdx.x / JC;   // 0..127 I-tile
  const int jc = blockIdx.x % JC;
  const int i0 = bi*64 + w*16;

  // i-side fragments (B-operand after swap): row i0+r16, k = q*8 (lo) / +32 (hi)
  const __bf16* z1r = Z1h + (size_t)(i0 + r16)*HID + q*8;
  const __bf16* z2r = Z2h + (size_t)(i0 + r16)*HID + q*8;
  const bf16x8 a1lo = *(const bf16x8*)(z1r);
  const bf16x8 a1hi = *(const bf16x8*)(z1r + 32);
  const bf16x8 a2lo = *(const bf16x8*)(z2r);
  const bf16x8 a2hi = *(const bf16x8*)(z2r + 32);

  float s1 = 0.f, n1 = 0.f, s2 = 0.f, n2 = 0.f;

  const int jbeg = jc * (N/JC);               // 512-wide sweep, 16 steps of 32
  const float Cexp = 1.8033688011112042f;     // 1/(TAU*ln2), TAU=0.8
  const float* prow = pos + (size_t)(i0 + r16)*N + q*4;

  #pragma unroll 1
  for (int j0 = jbeg; j0 < jbeg + (N/JC); j0 += 32) {
    bf16x8 b2l[2], b2h[2], b1l[2], b1h[2];
    f32x4 pv[2];
    #pragma unroll
    for (int c = 0; c < 2; ++c) {
      const __bf16* zj2 = Z2h + (size_t)(j0 + c*16 + r16)*HID + q*8;
      const __bf16* zj1 = Z1h + (size_t)(j0 + c*16 + r16)*HID + q*8;
      b2l[c] = *(const bf16x8*)(zj2);
      b2h[c] = *(const bf16x8*)(zj2 + 32);
      b1l[c] = *(const bf16x8*)(zj1);
      b1h[c] = *(const bf16x8*)(zj1 + 32);
      pv[c]  = *(const f32x4*)(prow + j0 + c*16);
    }
    #pragma unroll
    for (int c = 0; c < 2; ++c) {
      f32x4 zero4 = {0.f,0.f,0.f,0.f};
      f32x4 d1 = __builtin_amdgcn_mfma_f32_16x16x32_bf16(b2l[c], a1lo, zero4, 0,0,0);
      d1       = __builtin_amdgcn_mfma_f32_16x16x32_bf16(b2h[c], a1hi, d1,    0,0,0);
      f32x4 d2 = __builtin_amdgcn_mfma_f32_16x16x32_bf16(b1l[c], a2lo, zero4, 0,0,0);
      d2       = __builtin_amdgcn_mfma_f32_16x16x32_bf16(b1h[c], a2hi, d2,    0,0,0);
      #pragma unroll
      for (int r = 0; r < 4; ++r) {
        float e1 = exp2f(d1[r] * Cexp);
        float e2 = exp2f(d2[r] * Cexp);
        s1 += e1; n1 += e1 * pv[c][r];
        s2 += e2; n2 += e2 * pv[c][r];
      }
    }
  }

  // reduce j-partials across the 4 quads (xor 16, 32) -> full sums per row i0+r16
  s1 += __shfl_xor(s1, 16); s1 += __shfl_xor(s1, 32);
  n1 += __shfl_xor(n1, 16); n1 += __shfl_xor(n1, 32);
  s2 += __shfl_xor(s2, 16); s2 += __shfl_xor(s2, 32);
  n2 += __shfl_xor(n2, 16); n2 += __shfl_xor(n2, 32);

  if (lane < 16) {
    int row = i0 + r16;
    atomicAdd(&rowsum1[row], s1);
    atomicAdd(&num1[row],    n1);
    atomicAdd(&rowsum2[row], s2);
    atomicAdd(&num2[row],    n2);
  }
}

// ---------------- Kernel C: final loss reduction ----------------
__global__ __launch_bounds__(1024) void loss_kernel(
    const float* __restrict__ rowsum1, const float* __restrict__ num1,
    const float* __restrict__ rowsum2, const float* __restrict__ num2,
    float* __restrict__ out)
{
  __shared__ float part[16];
  const int tid = threadIdx.x, lane = tid & 63, w = tid >> 6;
  float acc = 0.f;
  for (int i = tid; i < N; i += 1024) {
    float sc = -logf(num1[i]/(rowsum1[i]+1e-8f) + 1e-8f);
    float mp = -logf(num2[i]/(rowsum2[i]+1e-8f) + 1e-8f);
    acc += 0.5f*sc + 0.5f*mp;   // LAMBDA = 0.5
  }
  #pragma unroll
  for (int m = 1; m < 64; m <<= 1) acc += __shfl_xor(acc, m);
  if (lane == 0) part[w] = acc;
  __syncthreads();
  if (tid == 0) {
    float t = 0.f;
    #pragma unroll
    for (int k = 0; k < 16; ++k) t += part[k];
    out[0] = t * (1.0f/N);
  }
}

extern "C" void kernel_launch(void* const* d_in, const int* in_sizes, int n_in,
                              void* d_out, int out_size, void* d_ws, size_t ws_size,
                              hipStream_t stream) {
  const float* x1  = (const float*)d_in[0];
  const float* x2  = (const float*)d_in[1];
  const float* W1  = (const float*)d_in[2];
  const float* b1  = (const float*)d_in[3];
  const float* W2  = (const float*)d_in[4];
  const float* b2  = (const float*)d_in[5];
  const float* pos = (const float*)d_in[6];

  char* ws = (char*)d_ws;
  __bf16* Z1h = (__bf16*)ws;
  __bf16* Z2h = (__bf16*)(ws + (size_t)N*HID*sizeof(__bf16));
  size_t zbytes = (size_t)2*N*HID*sizeof(__bf16);   // 2 MB
  float* rowsum1 = (float*)(ws + zbytes);
  float* num1    = rowsum1 + N;
  float* rowsum2 = num1 + N;
  float* num2    = rowsum2 + N;

  proj_kernel<<<1024, 256, 0, stream>>>(x1, x2, W1, b1, W2, b2, Z1h, Z2h, rowsum1);
  sim_kernel<<<128*JC, 256, 0, stream>>>(Z1h, Z2h, pos, rowsum1, num1, rowsum2, num2);
  loss_kernel<<<1, 1024, 0, stream>>>(rowsum1, num1, rowsum2, num2, (float*)d_out);
}

// Round 6
// 438.226 us; speedup vs baseline: 1.2040x; 1.0553x over previous
//
#include <hip/hip_runtime.h>
#include <hip/hip_bf16.h>

#define N 8192
#define HID 64
#define JC 8    // J-chunks per I-tile: grid = 128*JC = 1024 blocks, 4/CU resident

typedef __attribute__((ext_vector_type(4))) float f32x4;
typedef __attribute__((ext_vector_type(8))) __bf16 bf16x8;

// async global->LDS, 16B per lane, dest = wave-uniform base + lane*16
__device__ __forceinline__ void gload_lds16(const float* g, float* l) {
  __builtin_amdgcn_global_load_lds(
      (const __attribute__((address_space(1))) void*)g,
      (__attribute__((address_space(3))) void*)l, 16, 0, 0);
}

// ---------------- Kernel A: projection + L2 normalize -> bf16 ----------------
// h = elu(x @ W1^T + b1); z = h @ W2^T + b2; zhat = z / max(||z||, 1e-12)
// One wave per row-iteration; lane j = output feature j. W1/W2 in LDS with
// stride-68 padding. Also zero-inits the 4*N stat array (replaces memset).
__global__ __launch_bounds__(256) void proj_kernel(
    const float* __restrict__ x1, const float* __restrict__ x2,
    const float* __restrict__ W1, const float* __restrict__ b1,
    const float* __restrict__ W2, const float* __restrict__ b2,
    __bf16* __restrict__ Z1h, __bf16* __restrict__ Z2h,
    float* __restrict__ stats)
{
  __shared__ __align__(16) float w1s[64*68];
  __shared__ __align__(16) float w2s[64*68];
  __shared__ __align__(16) float xs[4][64];
  __shared__ __align__(16) float hs[4][64];

  const int tid  = threadIdx.x;
  const int lane = tid & 63;
  const int w    = tid >> 6;

  int gtid = blockIdx.x * 256 + tid;
  if (gtid < 4*N) stats[gtid] = 0.f;

  for (int idx = tid; idx < 64*64; idx += 256) {
    int j = idx >> 6, k = idx & 63;
    w1s[j*68+k] = W1[idx];
    w2s[j*68+k] = W2[idx];
  }
  __syncthreads();

  const float bias1 = b1[lane];
  const float bias2 = b2[lane];

  const int wave_global = blockIdx.x * 4 + w;   // 0..4095 with grid=1024
  #pragma unroll 1
  for (int it = 0; it < 4; ++it) {
    int R = wave_global * 4 + it;               // 0..16383
    const float* src; __bf16* dst;
    if (R < N) { src = x1 + (size_t)R*HID;      dst = Z1h + (size_t)R*HID; }
    else       { src = x2 + (size_t)(R-N)*HID;  dst = Z2h + (size_t)(R-N)*HID; }

    float xv = src[lane];
    xs[w][lane] = xv;
    float acc = bias1;
    #pragma unroll
    for (int qq = 0; qq < 16; ++qq) {
      f32x4 xq = *(const f32x4*)&xs[w][qq*4];
      f32x4 wq = *(const f32x4*)&w1s[lane*68 + qq*4];
      acc += xq.x*wq.x + xq.y*wq.y + xq.z*wq.z + xq.w*wq.w;
    }
    float h = acc > 0.f ? acc : expm1f(acc);             // ELU (alpha=1)
    hs[w][lane] = h;
    float acc2 = bias2;
    #pragma unroll
    for (int qq = 0; qq < 16; ++qq) {
      f32x4 hq = *(const f32x4*)&hs[w][qq*4];
      f32x4 wq = *(const f32x4*)&w2s[lane*68 + qq*4];
      acc2 += hq.x*wq.x + hq.y*wq.y + hq.z*wq.z + hq.w*wq.w;
    }
    float z = acc2;
    float ss = z*z;
    #pragma unroll
    for (int m = 1; m < 64; m <<= 1) ss += __shfl_xor(ss, m);
    float inv = 1.0f / fmaxf(sqrtf(ss), 1e-12f);
    dst[lane] = (__bf16)(z * inv);
  }
}

// ---------------- Kernel B: exp-sim with async LDS-staged pos ----------------
// Latency-bound -> streaming: pos tiles are staged to LDS via global_load_lds
// (async, 16B/lane) one 64-col super-step ahead, wave-PRIVATE (each wave stages
// and consumes only its own 16 i-rows) -> no __syncthreads, only a per-wave
// counted s_waitcnt vmcnt(4) (vmcnt retires in-order: <=4 outstanding means
// everything older than the 4 just-issued stage loads has landed).
// Bank-conflict fix: 16B col-slot XOR-swizzled by (row&7), applied on the
// GLOBAL source address at stage time (LDS dest must stay linear) and on the
// LDS read index. Swapped-operand MFMA (verified absmax 0): lane (q,r16),
// reg r = element (i = i0+r16, j = j0+c*16+q*4+r) -> pos quad = one f32x4.
__global__ __launch_bounds__(256) void sim_kernel(
    const __bf16* __restrict__ Z1h, const __bf16* __restrict__ Z2h,
    const float* __restrict__ pos,
    float* __restrict__ rowsum1, float* __restrict__ num1,
    float* __restrict__ rowsum2, float* __restrict__ num2)
{
  __shared__ __align__(16) float pbuf[2][64][64];   // 32 KB double buffer

  const int tid  = threadIdx.x;
  const int lane = tid & 63;
  const int w    = tid >> 6;
  const int r16  = lane & 15;
  const int q    = lane >> 4;

  const int bi  = blockIdx.x / JC;    // 0..127 I-tile
  const int jc  = blockIdx.x % JC;
  const int i0b = bi*64;
  const int i0  = i0b + w*16;

  // i-side fragments: row i0+r16, k = q*8 (lo) / +32 (hi)
  const __bf16* z1r = Z1h + (size_t)(i0 + r16)*HID + q*8;
  const __bf16* z2r = Z2h + (size_t)(i0 + r16)*HID + q*8;
  const bf16x8 a1lo = *(const bf16x8*)(z1r);
  const bf16x8 a1hi = *(const bf16x8*)(z1r + 32);
  const bf16x8 a2lo = *(const bf16x8*)(z2r);
  const bf16x8 a2hi = *(const bf16x8*)(z2r + 32);

  float s1 = 0.f, n1 = 0.f, s2 = 0.f, n2 = 0.f;

  const int jbeg = jc * (N/JC);               // 1024-col chunk, 16 x 64-col steps
  const float Cexp = 1.8033688011112042f;     // 1/(TAU*ln2), TAU=0.8

  // stage one 64-col pos tile for this wave's 16 rows: 4 x global_load_lds.
  // lane l -> LDS byte (w*16+rr*4)*256 + l*16 = row (w*16+rr*4+(l>>4)), slot (l&15)
  // source col-slot = slot ^ (row&7)  (inverse of the read-side swizzle)
#define STAGE(BUF, JJ) { \
    _Pragma("unroll") \
    for (int rr = 0; rr < 4; ++rr) { \
      int row_t = w*16 + rr*4 + (lane >> 4); \
      int slot  = lane & 15; \
      const float* gsrc = pos + (size_t)(i0b + row_t)*N + (JJ) + (((slot ^ (row_t & 7))) << 2); \
      gload_lds16(gsrc, &pbuf[BUF][w*16 + rr*4][0]); \
    } }

  STAGE(0, jbeg)

  int cur = 0;
  #pragma unroll 1
  for (int ss = 0; ss < 16; ++ss) {
    const int jj = jbeg + ss*64;
    if (ss != 15) {
      STAGE(cur ^ 1, jj + 64)
      asm volatile("s_waitcnt vmcnt(4)" ::: "memory");  // cur's 4 stage loads done
    } else {
      asm volatile("s_waitcnt vmcnt(0)" ::: "memory");
    }
    __builtin_amdgcn_sched_barrier(0);

    #pragma unroll
    for (int cc = 0; cc < 64; cc += 32) {
      const int j0 = jj + cc;
      bf16x8 b2l[2], b2h[2], b1l[2], b1h[2];
      f32x4 pv[2];
      #pragma unroll
      for (int c = 0; c < 2; ++c) {
        const __bf16* zj2 = Z2h + (size_t)(j0 + c*16 + r16)*HID + q*8;
        const __bf16* zj1 = Z1h + (size_t)(j0 + c*16 + r16)*HID + q*8;
        b2l[c] = *(const bf16x8*)(zj2);
        b2h[c] = *(const bf16x8*)(zj2 + 32);
        b1l[c] = *(const bf16x8*)(zj1);
        b1h[c] = *(const bf16x8*)(zj1 + 32);
        int g = (cc >> 2) + c*4 + q;          // global 16B col-slot 0..15
        int s = g ^ (r16 & 7);                // swizzled LDS slot
        pv[c] = *(const f32x4*)&pbuf[cur][w*16 + r16][s*4];
      }
      #pragma unroll
      for (int c = 0; c < 2; ++c) {
        f32x4 zero4 = {0.f,0.f,0.f,0.f};
        f32x4 d1 = __builtin_amdgcn_mfma_f32_16x16x32_bf16(b2l[c], a1lo, zero4, 0,0,0);
        d1       = __builtin_amdgcn_mfma_f32_16x16x32_bf16(b2h[c], a1hi, d1,    0,0,0);
        f32x4 d2 = __builtin_amdgcn_mfma_f32_16x16x32_bf16(b1l[c], a2lo, zero4, 0,0,0);
        d2       = __builtin_amdgcn_mfma_f32_16x16x32_bf16(b1h[c], a2hi, d2,    0,0,0);
        #pragma unroll
        for (int r = 0; r < 4; ++r) {
          float e1 = exp2f(d1[r] * Cexp);
          float e2 = exp2f(d2[r] * Cexp);
          s1 += e1; n1 += e1 * pv[c][r];
          s2 += e2; n2 += e2 * pv[c][r];
        }
      }
    }
    cur ^= 1;
  }
#undef STAGE

  // reduce j-partials across the 4 quads -> full sums per row i0+r16
  s1 += __shfl_xor(s1, 16); s1 += __shfl_xor(s1, 32);
  n1 += __shfl_xor(n1, 16); n1 += __shfl_xor(n1, 32);
  s2 += __shfl_xor(s2, 16); s2 += __shfl_xor(s2, 32);
  n2 += __shfl_xor(n2, 16); n2 += __shfl_xor(n2, 32);

  if (lane < 16) {
    int row = i0 + r16;
    atomicAdd(&rowsum1[row], s1);
    atomicAdd(&num1[row],    n1);
    atomicAdd(&rowsum2[row], s2);
    atomicAdd(&num2[row],    n2);
  }
}

// ---------------- Kernel C: final loss reduction ----------------
__global__ __launch_bounds__(1024) void loss_kernel(
    const float* __restrict__ rowsum1, const float* __restrict__ num1,
    const float* __restrict__ rowsum2, const float* __restrict__ num2,
    float* __restrict__ out)
{
  __shared__ float part[16];
  const int tid = threadIdx.x, lane = tid & 63, w = tid >> 6;
  float acc = 0.f;
  for (int i = tid; i < N; i += 1024) {
    float sc = -logf(num1[i]/(rowsum1[i]+1e-8f) + 1e-8f);
    float mp = -logf(num2[i]/(rowsum2[i]+1e-8f) + 1e-8f);
    acc += 0.5f*sc + 0.5f*mp;   // LAMBDA = 0.5
  }
  #pragma unroll
  for (int m = 1; m < 64; m <<= 1) acc += __shfl_xor(acc, m);
  if (lane == 0) part[w] = acc;
  __syncthreads();
  if (tid == 0) {
    float t = 0.f;
    #pragma unroll
    for (int k = 0; k < 16; ++k) t += part[k];
    out[0] = t * (1.0f/N);
  }
}

extern "C" void kernel_launch(void* const* d_in, const int* in_sizes, int n_in,
                              void* d_out, int out_size, void* d_ws, size_t ws_size,
                              hipStream_t stream) {
  const float* x1  = (const float*)d_in[0];
  const float* x2  = (const float*)d_in[1];
  const float* W1  = (const float*)d_in[2];
  const float* b1  = (const float*)d_in[3];
  const float* W2  = (const float*)d_in[4];
  const float* b2  = (const float*)d_in[5];
  const float* pos = (const float*)d_in[6];

  char* ws = (char*)d_ws;
  __bf16* Z1h = (__bf16*)ws;
  __bf16* Z2h = (__bf16*)(ws + (size_t)N*HID*sizeof(__bf16));
  size_t zbytes = (size_t)2*N*HID*sizeof(__bf16);   // 2 MB
  float* rowsum1 = (float*)(ws + zbytes);
  float* num1    = rowsum1 + N;
  float* rowsum2 = num1 + N;
  float* num2    = rowsum2 + N;

  proj_kernel<<<1024, 256, 0, stream>>>(x1, x2, W1, b1, W2, b2, Z1h, Z2h, rowsum1);
  sim_kernel<<<128*JC, 256, 0, stream>>>(Z1h, Z2h, pos, rowsum1, num1, rowsum2, num2);
  loss_kernel<<<1, 1024, 0, stream>>>(rowsum1, num1, rowsum2, num2, (float*)d_out);
}